// Round 16
// baseline (1669.356 us; speedup 1.0000x reference)
//
#include <hip/hip_runtime.h>

#define T_ 512
#define K_ 128
#define B_ 256

// Viterbi max-scores streamed by the serial wave, consumed by the in-kernel
// bp phase and last-tag argmax. Exact fp32 -> bp recompute is bit-identical.
__device__ float g_v[B_][T_][K_];   // 64 MB module-static (no hipMalloc)

// History: 697 (R5) -> 548 (R8 role-split) -> 494.6 (R10 champion) ->
// R11 658 / R12 505 (nulls) -> R15 barrier-free 4-kernel: 1494 us, CONFOUNDED
// by register demotion (VGPR=144: compiler rematerialized the 256-float
// transition tables as per-step L2 loads at occupancy 1 -> latency disaster)
// + ~200 us of multi-kernel dispatch gaps.
// R16: ONE fused kernel per sequence (256 blocks x 256 thr, 1 block/CU):
//   wave 0 = fwd serial (barrier-free single-wave LDS state),
//   wave 1 = vit value-only serial (streams v_t to g_v),
//   waves 2-3 wait; then ALL 4 waves recompute backpointers t-parallel
//   (bit-identical tournament, verified absmax 0.0 in R15) into LDS,
//   then backtrace/decode/score epilogue. Register tables forced resident
//   with asm keep-alive (compiler cannot rematerialize through asm).

__global__ __launch_bounds__(256, 1) void crf_fused(
    const float* __restrict__ emissions,
    const int* __restrict__ tag_ids,
    const int* __restrict__ lengths,
    const float* __restrict__ transitions,
    float* __restrict__ out,
    float* __restrict__ ws_ll,
    int* __restrict__ ws_cnt)
{
    __shared__ __align__(16) float ea[K_];               // fwd state (wave 0 only)
    __shared__ __align__(16) float va[K_];               // vit state (wave 1 only)
    __shared__ unsigned char bpL[T_ * K_];               // 64 KB backpointers
    __shared__ unsigned char decL[T_];
    __shared__ float redS[4];
    __shared__ int  redI[4];
    __shared__ int  ltag;
    __shared__ float logZsh;

    const int b   = blockIdx.x;
    const int tid = threadIdx.x;
    const int wid = tid >> 6;
    const int l   = tid & 63;
    const int len = lengths[b];
    const float* emB = emissions + (size_t)b * T_ * K_;
    const int*  tagB = tag_ids + b * T_;

    if (wid == 0) {
        // ---------- FORWARD serial (single wave, no barriers) ----------
        float tA[128], tB[128];
        #pragma unroll
        for (int i = 0; i < 128; ++i) {
            tA[i] = __expf(transitions[i * K_ + l]);
            tB[i] = __expf(transitions[i * K_ + l + 64]);
        }
        #pragma unroll
        for (int i = 0; i < 128; ++i) {                  // force VGPR residency
            asm volatile("" : "+v"(tA[i]));
            asm volatile("" : "+v"(tB[i]));
        }

        float e0 = emB[l], e1 = emB[l + 64];
        ea[l]      = __expf(e0);                         // offset S0 = 0
        ea[l + 64] = __expf(e1);
        float wm = fmaxf(e0, e1);
        #pragma unroll
        for (int m = 1; m < 64; m <<= 1) wm = fmaxf(wm, __shfl_xor(wm, m));
        float Wm = wm;
        float Sr = 0.f;

        float eN0 = emB[K_ + l], eN1 = emB[K_ + l + 64];

        for (int t = 1; t < len; ++t) {
            float ec0 = eN0, ec1 = eN1;
            int tn = (t + 1 < T_) ? (t + 1) : t;
            eN0 = emB[tn * K_ + l]; eN1 = emB[tn * K_ + l + 64];

            float Sw = (((t - 1) & 3) == 0) ? Wm : Sr;   // defer-max cadence 4

            float a0=0.f,a1=0.f,a2=0.f,a3=0.f, c0=0.f,c1=0.f,c2=0.f,c3=0.f;
            #pragma unroll
            for (int m = 0; m < 32; ++m) {
                float4 q = *(const float4*)&ea[4 * m];   // broadcast read
                a0 = fmaf(q.x, tA[4*m+0], a0);
                a1 = fmaf(q.y, tA[4*m+1], a1);
                a2 = fmaf(q.z, tA[4*m+2], a2);
                a3 = fmaf(q.w, tA[4*m+3], a3);
                c0 = fmaf(q.x, tB[4*m+0], c0);
                c1 = fmaf(q.y, tB[4*m+1], c1);
                c2 = fmaf(q.z, tB[4*m+2], c2);
                c3 = fmaf(q.w, tB[4*m+3], c3);
            }
            float d0 = (a0 + a1) + (a2 + a3);
            float d1 = (c0 + c1) + (c2 + c3);
            float an0 = __logf(d0) + Sr + ec0;
            float an1 = __logf(d1) + Sr + ec1;
            ea[l]      = __expf(an0 - Sw);               // wave-lockstep: reads done
            ea[l + 64] = __expf(an1 - Sw);
            Sr = Sw;
            if (((t - 1) & 3) == 3) {
                float w = fmaxf(an0, an1);
                #pragma unroll
                for (int m = 1; m < 64; m <<= 1) w = fmaxf(w, __shfl_xor(w, m));
                Wm = w;
            }
        }
        float s = ea[l] + ea[l + 64];
        #pragma unroll
        for (int m = 1; m < 64; m <<= 1) s += __shfl_xor(s, m);
        if (l == 0) logZsh = Sr + __logf(s);

    } else if (wid == 1) {
        // ---------- VITERBI value-only serial (single wave) ----------
        float tA[128], tB[128];
        #pragma unroll
        for (int i = 0; i < 128; ++i) {
            tA[i] = transitions[i * K_ + l];
            tB[i] = transitions[i * K_ + l + 64];
        }
        #pragma unroll
        for (int i = 0; i < 128; ++i) {                  // force VGPR residency
            asm volatile("" : "+v"(tA[i]));
            asm volatile("" : "+v"(tB[i]));
        }

        float v0 = emB[l], v1 = emB[l + 64];
        va[l] = v0; va[l + 64] = v1;
        g_v[b][0][l] = v0; g_v[b][0][l + 64] = v1;

        float eN0 = emB[K_ + l], eN1 = emB[K_ + l + 64];

        for (int t = 1; t < len; ++t) {
            float ec0 = eN0, ec1 = eN1;
            int tn = (t + 1 < T_) ? (t + 1) : t;
            eN0 = emB[tn * K_ + l]; eN1 = emB[tn * K_ + l + 64];

            // fp max is exactly associative: any grouping = argmax-path value
            float r0 = -3.4028235e38f, r1 = r0, r2 = r0, r3 = r0;
            #pragma unroll
            for (int m = 0; m < 32; ++m) {
                float4 q = *(const float4*)&va[4 * m];
                r0 = fmaxf(r0, fmaxf(q.x + tA[4*m+0], q.y + tA[4*m+1]));
                r1 = fmaxf(r1, fmaxf(q.z + tA[4*m+2], q.w + tA[4*m+3]));
                r2 = fmaxf(r2, fmaxf(q.x + tB[4*m+0], q.y + tB[4*m+1]));
                r3 = fmaxf(r3, fmaxf(q.z + tB[4*m+2], q.w + tB[4*m+3]));
            }
            float vn0 = fmaxf(r0, r1) + ec0;
            float vn1 = fmaxf(r2, r3) + ec1;
            va[l] = vn0; va[l + 64] = vn1;
            g_v[b][t][l] = vn0; g_v[b][t][l + 64] = vn1; // fire-and-forget
        }
    }
    // waves 2-3 arrive immediately; serial waves arrive when done
    __syncthreads();

    // ---------- bp phase: all 4 waves, t-parallel (independent t's) ----------
    {
        const int j = tid >> 1;
        const int c = tid & 1;
        float tbl[64];
        #pragma unroll
        for (int k = 0; k < 64; ++k)
            tbl[k] = transitions[(c * 64 + k) * K_ + j];

        for (int t = 1; t < len; ++t) {
            const float* vp = &g_v[b][t - 1][c * 64];
            // exact R10/R15 first-max tournament -> bit-identical backpointers
            float v0[16]; int gg[16];
            #pragma unroll
            for (int k = 0; k < 16; ++k) {
                float4 v4 = *(const float4*)(vp + 4 * k);
                float s0 = v4.x + tbl[4*k+0];
                float s1 = v4.y + tbl[4*k+1];
                float s2 = v4.z + tbl[4*k+2];
                float s3 = v4.w + tbl[4*k+3];
                float mA; int aA;
                if (s1 > s0) { mA = s1; aA = 4*k+1; } else { mA = s0; aA = 4*k+0; }
                float mC; int aC;
                if (s3 > s2) { mC = s3; aC = 4*k+3; } else { mC = s2; aC = 4*k+2; }
                if (mC > mA) { v0[k] = mC; gg[k] = aC; } else { v0[k] = mA; gg[k] = aA; }
            }
            #pragma unroll
            for (int st = 1; st < 16; st <<= 1) {
                #pragma unroll
                for (int k = 0; k < 16; k += 2 * st) {
                    if (v0[k+st] > v0[k]) { v0[k] = v0[k+st]; gg[k] = gg[k+st]; }
                }
            }
            float mB = v0[0];
            int  arg = gg[0] + c * 64;
            float om = __shfl_xor(mB, 1);
            int   oa = __shfl_xor(arg, 1);
            float mLow  = c ? om : mB;   int aLow  = c ? oa : arg;  // low-i wins ties
            float mHigh = c ? mB : om;   int aHigh = c ? arg : oa;
            int aF = (mHigh > mLow) ? aHigh : aLow;
            if (c == 0) bpL[t * K_ + j] = (unsigned char)aF;
        }
    }

    // ---------- sequence score (overlaps nothing; all threads free) ----------
    {
        float s = 0.f;
        #pragma unroll
        for (int h = 0; h < 2; ++h) {
            int t = tid + h * 256;
            if (t < len) {
                int tg = tagB[t];
                float v = emB[t * K_ + tg];
                if (t >= 1) v += transitions[tagB[t - 1] * K_ + tg];
                s += v;
            }
        }
        #pragma unroll
        for (int m = 1; m < 64; m <<= 1) s += __shfl_xor(s, m);
        if ((tid & 63) == 0) redS[tid >> 6] = s;
    }
    __syncthreads();

    // ---------- last tag: first-max over final viterbi scores ----------
    if (tid < 64) {
        const float* vf = &g_v[b][len - 1][0];
        float m = vf[tid]; int a = tid;
        float v2 = vf[tid + 64];
        if (v2 > m) { m = v2; a = tid + 64; }
        #pragma unroll
        for (int sft = 1; sft < 64; sft <<= 1) {
            float om = __shfl_xor(m, sft);
            int   oa = __shfl_xor(a, sft);
            if (om > m || (om == m && oa < a)) { m = om; a = oa; }
        }
        if (tid == 0) ltag = a;
    }
    __syncthreads();

    // ---------- backtrace (serial chain through LDS) ----------
    if (tid == 0) {
        int tg = ltag;
        for (int t = T_ - 1; t >= 1; --t) {
            decL[t] = (unsigned char)tg;
            if (t < len) tg = bpL[t * K_ + tg];          // identity bp for t >= len
        }
        decL[0] = (unsigned char)tg;
    }
    __syncthreads();

    // ---------- decode write + accuracy ----------
    {
        int good = 0;
        #pragma unroll
        for (int h = 0; h < 2; ++h) {
            int t = tid + h * 256;
            int dv = decL[t];
            out[1 + b * T_ + t] = (float)dv;
            good += (t < len && tagB[t] == dv) ? 1 : 0;
        }
        #pragma unroll
        for (int m = 1; m < 64; m <<= 1) good += __shfl_xor(good, m);
        if ((tid & 63) == 0) redI[tid >> 6] = good;
    }
    __syncthreads();

    if (tid == 0) {
        ws_cnt[b] = redI[0] + redI[1] + redI[2] + redI[3];
        ws_ll[b]  = (redS[0] + redS[1] + redS[2] + redS[3]) - logZsh;
    }
}

// Final reduction: loss = -mean(ll), accuracy = sum(correct)/sum(len)
__global__ void crf_final(const float* __restrict__ ws_ll,
                          const int* __restrict__ ws_cnt,
                          const int* __restrict__ lengths,
                          float* __restrict__ out)
{
    __shared__ float sll[4];
    __shared__ int scnt[4], slen[4];
    int tid = threadIdx.x;                               // blockDim == B_ == 256
    float ll = ws_ll[tid];
    int   cn = ws_cnt[tid];
    int   L  = lengths[tid];
    #pragma unroll
    for (int m = 1; m < 64; m <<= 1) {
        ll += __shfl_xor(ll, m);
        cn += __shfl_xor(cn, m);
        L  += __shfl_xor(L, m);
    }
    if ((tid & 63) == 0) { sll[tid >> 6] = ll; scnt[tid >> 6] = cn; slen[tid >> 6] = L; }
    __syncthreads();
    if (tid == 0) {
        float llS = sll[0] + sll[1] + sll[2] + sll[3];
        int   cS  = scnt[0] + scnt[1] + scnt[2] + scnt[3];
        int   LS  = slen[0] + slen[1] + slen[2] + slen[3];
        out[0] = -llS / (float)B_;
        out[1 + B_ * T_] = (float)cS / (float)LS;
    }
}

extern "C" void kernel_launch(void* const* d_in, const int* in_sizes, int n_in,
                              void* d_out, int out_size, void* d_ws, size_t ws_size,
                              hipStream_t stream) {
    const float* emissions   = (const float*)d_in[0];
    const int*   tag_ids     = (const int*)d_in[1];
    const int*   lengths     = (const int*)d_in[2];
    const float* transitions = (const float*)d_in[3];
    float* out = (float*)d_out;

    float* ws_ll  = (float*)d_ws;
    int*   ws_cnt = (int*)((char*)d_ws + B_ * sizeof(float));

    crf_fused<<<B_, 256, 0, stream>>>(emissions, tag_ids, lengths, transitions,
                                      out, ws_ll, ws_cnt);
    crf_final<<<1, B_, 0, stream>>>(ws_ll, ws_cnt, lengths, out);
}

// Round 17
// 562.526 us; speedup vs baseline: 2.9676x; 2.9676x over previous
//
#include <hip/hip_runtime.h>

#define T_ 512
#define K_ 128
#define B_ 256
#define PADH 68      // dword stride between i-halves (64 + 4 skew, 16B-aligned)

// CHAMPION (R10, measured 494.6 us, absmax 0.0, bank conflicts 0).
// Role-split grid: blocks [0,256) = forward, blocks [256,512) = viterbi.
// History: 697 (R5 fused 8-wave) -> 548 (R8 role-split) -> 494.6 (R10: skewed
// broadcast LDS + tournament argmax). Falsified alternatives: C=2 layout (R11,
// 658 — longer dep chains beat fewer LDS reads); length-decorrelation +
// lgkm-only barrier (R12, 505); barrier-free fat-register serial wave (R15/R16,
// 1494/1669 — hipcc refuses >~148 VGPRs, rematerializes 256-float tables as
// per-step loads; design family closed).
// Layout per role block (256 thr = 4 waves): j = tid>>1, c = tid&1.
// State buffers skewed: half c at dword offset c*PADH; instruction k reads
// bank-quad 4k (c=0) vs 4k+4 (c=1) -> disjoint banks, pure broadcast, zero
// conflicts. Viterbi argmax = tournament tree (first-max-wins at every level
// == jnp.argmax), dep depth ~6 levels. Forward: defer-max cadence 4.

__global__ __launch_bounds__(256, 2) void crf_main(
    const float* __restrict__ emissions,
    const int* __restrict__ tag_ids,
    const int* __restrict__ lengths,
    const float* __restrict__ transitions,
    float* __restrict__ out,
    float* __restrict__ ws_ll,
    int* __restrict__ ws_cnt)
{
    const int bid = blockIdx.x;
    const int tid = threadIdx.x;

    if (bid < B_) {
        // ==================== FORWARD block ====================
        __shared__ __align__(16) float eaBuf[2][2 * PADH]; // exp(alpha-S), skewed dbuf
        __shared__ __align__(16) float wmax[4];            // per-wave max of alpha
        __shared__ float redLDS[4];                        // score partials

        const int b   = bid;
        const int len = lengths[b];
        const float* emB = emissions + (size_t)b * T_ * K_;
        const int*  tagB = tag_ids + b * T_;

        // ---- sequence score (unary + binary), 2 t per thread ----
        {
            float s = 0.f;
            #pragma unroll
            for (int h = 0; h < 2; ++h) {
                int t = tid + h * 256;
                if (t < len) {
                    int tg = tagB[t];
                    float v = emB[t * K_ + tg];
                    if (t >= 1) v += transitions[tagB[t - 1] * K_ + tg];
                    s += v;
                }
            }
            #pragma unroll
            for (int m = 1; m < 64; m <<= 1) s += __shfl_xor(s, m);
            if ((tid & 63) == 0) redLDS[tid >> 6] = s;
        }

        const int j = tid >> 1;
        const int c = tid & 1;
        const int wiA = (j >> 6) * PADH + (j & 63);        // skewed write index

        float tbl[64];
        #pragma unroll
        for (int k = 0; k < 64; ++k)
            tbl[k] = __expf(transitions[(c * 64 + k) * K_ + j]);

        // ---- init t = 0 (offset S0 = 0) ----
        {
            float e0 = emB[j];
            if (c == 0) eaBuf[0][wiA] = __expf(e0);
            float wm = e0;
            #pragma unroll
            for (int m = 1; m < 64; m <<= 1) wm = fmaxf(wm, __shfl_xor(wm, m));
            if ((tid & 63) == 0) wmax[tid >> 6] = wm;
        }
        __syncthreads();

        int cur = 0;
        float Sr = 0.f;                                // scale of current ea buffer
        float emN = emB[K_ + j];                       // prefetch t = 1

        for (int t = 1; t < len; ++t) {
            float emC = emN;
            int tn = (t + 1 < T_) ? (t + 1) : t;
            emN = emB[tn * K_ + j];                    // issue early, consume next step

            float Sw;
            if (((t - 1) & 3) == 0) {                  // window start: fresh scale
                float4 wv = *(const float4*)&wmax[0];
                Sw = fmaxf(fmaxf(wv.x, wv.y), fmaxf(wv.z, wv.w));
            } else Sw = Sr;

            const float* ea = &eaBuf[cur][c * PADH];
            float a0 = 0.f, a1 = 0.f, a2 = 0.f, a3 = 0.f;
            #pragma unroll
            for (int k = 0; k < 16; ++k) {
                float4 e4 = *(const float4*)(ea + 4 * k);
                a0 = fmaf(e4.x, tbl[4 * k + 0], a0);
                a1 = fmaf(e4.y, tbl[4 * k + 1], a1);
                a2 = fmaf(e4.z, tbl[4 * k + 2], a2);
                a3 = fmaf(e4.w, tbl[4 * k + 3], a3);
            }
            float dot = (a0 + a1) + (a2 + a3);
            dot += __shfl_xor(dot, 1);                 // combine the two i-halves

            float an = __logf(dot) + Sr + emC;
            if (c == 0) eaBuf[cur ^ 1][wiA] = __expf(an - Sw);
            Sr = Sw;

            if (((t - 1) & 3) == 3) {                  // window end: publish max
                float wm = an;
                #pragma unroll
                for (int m = 1; m < 64; m <<= 1) wm = fmaxf(wm, __shfl_xor(wm, m));
                if ((tid & 63) == 0) wmax[tid >> 6] = wm;
            }
            cur ^= 1;
            __syncthreads();
        }

        // ---- logZ + final write ----
        float logZv = 0.f;
        if (tid < 64) {
            float s = eaBuf[cur][tid] + eaBuf[cur][PADH + tid];
            #pragma unroll
            for (int m = 1; m < 64; m <<= 1) s += __shfl_xor(s, m);
            logZv = Sr + __logf(s);                    // valid in tid 0
        }
        if (tid == 0) {
            float sc = redLDS[0] + redLDS[1] + redLDS[2] + redLDS[3];
            ws_ll[b] = sc - logZv;
        }

    } else {
        // ==================== VITERBI block ====================
        __shared__ unsigned char bpLDS[T_ * K_];           // 64 KB backpointers
        __shared__ __align__(16) float vaBuf[2][2 * PADH]; // skewed dbuf
        __shared__ unsigned char decLDS[T_];               // decoded chain
        __shared__ int redILDS[4];                         // accuracy partials
        __shared__ int ltagLDS;

        const int b   = bid - B_;
        const int len = lengths[b];
        const float* emB = emissions + (size_t)b * T_ * K_;
        const int*  tagB = tag_ids + b * T_;

        const int j = tid >> 1;
        const int c = tid & 1;
        const int wiA = (j >> 6) * PADH + (j & 63);

        float tbl[64];
        #pragma unroll
        for (int k = 0; k < 64; ++k)
            tbl[k] = transitions[(c * 64 + k) * K_ + j];

        // ---- init t = 0 ----
        {
            float e0 = emB[j];
            if (c == 0) vaBuf[0][wiA] = e0;
        }
        __syncthreads();

        int cur = 0;
        float emN = emB[K_ + j];                       // prefetch t = 1

        for (int t = 1; t < len; ++t) {
            float emC = emN;
            int tn = (t + 1 < T_) ? (t + 1) : t;
            emN = emB[tn * K_ + j];

            const float* va = &vaBuf[cur][c * PADH];
            // tournament argmax: 16 independent group winners, then 4-level
            // tree; "take right only if strictly greater" at every level ==
            // lowest-index-among-maxima == first-max-wins.
            float v0[16];
            int   g0[16];
            #pragma unroll
            for (int k = 0; k < 16; ++k) {
                float4 v4 = *(const float4*)(va + 4 * k);
                float s0 = v4.x + tbl[4 * k + 0];
                float s1 = v4.y + tbl[4 * k + 1];
                float s2 = v4.z + tbl[4 * k + 2];
                float s3 = v4.w + tbl[4 * k + 3];
                float mA; int aA;
                if (s1 > s0) { mA = s1; aA = 4 * k + 1; } else { mA = s0; aA = 4 * k + 0; }
                float mC; int aC;
                if (s3 > s2) { mC = s3; aC = 4 * k + 3; } else { mC = s2; aC = 4 * k + 2; }
                if (mC > mA) { v0[k] = mC; g0[k] = aC; } else { v0[k] = mA; g0[k] = aA; }
            }
            #pragma unroll
            for (int st = 1; st < 16; st <<= 1) {
                #pragma unroll
                for (int k = 0; k < 16; k += 2 * st) {
                    if (v0[k + st] > v0[k]) { v0[k] = v0[k + st]; g0[k] = g0[k + st]; }
                }
            }
            float mB = v0[0];
            int  arg = g0[0] + c * 64;

            float om = __shfl_xor(mB, 1);
            int   oa = __shfl_xor(arg, 1);
            // low-i half wins ties
            float mLow  = c ? om : mB;   int aLow  = c ? oa : arg;
            float mHigh = c ? mB : om;   int aHigh = c ? arg : oa;
            float mF; int aF;
            if (mHigh > mLow) { mF = mHigh; aF = aHigh; } else { mF = mLow; aF = aLow; }
            if (c == 0) {
                vaBuf[cur ^ 1][wiA] = mF + emC;
                bpLDS[t * K_ + j] = (unsigned char)aF;
            }
            cur ^= 1;
            __syncthreads();
        }

        // ---- last tag: argmax_j v_final (first-max-wins) ----
        if (tid < 64) {
            int l = tid;
            float m = vaBuf[cur][l]; int a = l;
            float v2 = vaBuf[cur][PADH + l];
            if (v2 > m) { m = v2; a = l + 64; }
            #pragma unroll
            for (int sft = 1; sft < 64; sft <<= 1) {
                float om = __shfl_xor(m, sft);
                int   oa = __shfl_xor(a, sft);
                if (om > m || (om == m && oa < a)) { m = om; a = oa; }
            }
            if (l == 0) ltagLDS = a;
        }
        __syncthreads();

        // ---- backtrace (serial chain through LDS) ----
        if (tid == 0) {
            int tg = ltagLDS;
            for (int t = T_ - 1; t >= 1; --t) {
                decLDS[t] = (unsigned char)tg;
                if (t < len) tg = bpLDS[t * K_ + tg];  // identity bp for t >= len
            }
            decLDS[0] = (unsigned char)tg;
        }
        __syncthreads();

        // ---- decoded write + accuracy count, 2 t per thread ----
        {
            int good = 0;
            #pragma unroll
            for (int h = 0; h < 2; ++h) {
                int t = tid + h * 256;
                int dv = decLDS[t];
                out[1 + b * T_ + t] = (float)dv;
                good += (t < len && tagB[t] == dv) ? 1 : 0;
            }
            #pragma unroll
            for (int m = 1; m < 64; m <<= 1) good += __shfl_xor(good, m);
            if ((tid & 63) == 0) redILDS[tid >> 6] = good;
        }
        __syncthreads();

        if (tid == 0)
            ws_cnt[b] = redILDS[0] + redILDS[1] + redILDS[2] + redILDS[3];
    }
}

// Final reduction: loss = -mean(ll), accuracy = sum(correct)/sum(len)
__global__ void crf_final(const float* __restrict__ ws_ll,
                          const int* __restrict__ ws_cnt,
                          const int* __restrict__ lengths,
                          float* __restrict__ out)
{
    __shared__ float sll[4];
    __shared__ int scnt[4], slen[4];
    int tid = threadIdx.x;                            // blockDim == B_ == 256
    float ll = ws_ll[tid];
    int   cn = ws_cnt[tid];
    int   L  = lengths[tid];
    #pragma unroll
    for (int m = 1; m < 64; m <<= 1) {
        ll += __shfl_xor(ll, m);
        cn += __shfl_xor(cn, m);
        L  += __shfl_xor(L, m);
    }
    if ((tid & 63) == 0) { sll[tid >> 6] = ll; scnt[tid >> 6] = cn; slen[tid >> 6] = L; }
    __syncthreads();
    if (tid == 0) {
        float llS = sll[0] + sll[1] + sll[2] + sll[3];
        int   cS  = scnt[0] + scnt[1] + scnt[2] + scnt[3];
        int   LS  = slen[0] + slen[1] + slen[2] + slen[3];
        out[0] = -llS / (float)B_;
        out[1 + B_ * T_] = (float)cS / (float)LS;
    }
}

extern "C" void kernel_launch(void* const* d_in, const int* in_sizes, int n_in,
                              void* d_out, int out_size, void* d_ws, size_t ws_size,
                              hipStream_t stream) {
    const float* emissions   = (const float*)d_in[0];
    const int*   tag_ids     = (const int*)d_in[1];
    const int*   lengths     = (const int*)d_in[2];
    const float* transitions = (const float*)d_in[3];
    float* out = (float*)d_out;

    float* ws_ll  = (float*)d_ws;
    int*   ws_cnt = (int*)((char*)d_ws + B_ * sizeof(float));

    crf_main<<<2 * B_, 256, 0, stream>>>(emissions, tag_ids, lengths, transitions,
                                         out, ws_ll, ws_cnt);
    crf_final<<<1, B_, 0, stream>>>(ws_ll, ws_cnt, lengths, out);
}